// Round 15
// baseline (96.420 us; speedup 1.0000x reference)
//
#include <hip/hip_runtime.h>
#include <hip/hip_bf16.h>

#define NPIX   784
#define CIN    384
#define NHEADS 12
#define HDIM   32
#define MID    384
#define QKV_M  1152
#define LOG2E  1.4426950408889634f
#define QSCALE (0.17677669529663687f * 1.4426950408889634f)
#define W1SZ   442368   // 1152*384
#define W2SZ   147456   // 384*384
#define NBIAS  3025     // 55*55

typedef __attribute__((ext_vector_type(8))) short bf16x8;
typedef __attribute__((ext_vector_type(4))) float f32x4;
typedef __attribute__((ext_vector_type(4))) unsigned short ush4;
typedef __attribute__((ext_vector_type(2))) unsigned int u32x2;
typedef unsigned short u16;
typedef unsigned int u32;

__device__ __forceinline__ u16 f2bf(float f) {
  union { float f; u32 u; } v; v.f = f;
  u32 u = v.u;
  u += 0x7fffu + ((u >> 16) & 1u);
  return (u16)(u >> 16);
}
__device__ __forceinline__ u32 cvtpk_bf16(float lo, float hi) {
  u32 r;
  asm("v_cvt_pk_bf16_f32 %0, %1, %2" : "=v"(r) : "v"(lo), "v"(hi));
  return r;
}
// untracked global loads (vmcnt managed manually by the attn protocol)
__device__ __forceinline__ f32x4 gload16f(const float* p) {
  f32x4 r;
  asm volatile("global_load_dwordx4 %0, %1, off" : "=v"(r) : "v"(p) : "memory");
  return r;
}
__device__ __forceinline__ bf16x8 gload16b(const u16* p) {
  bf16x8 r;
  asm volatile("global_load_dwordx4 %0, %1, off" : "=v"(r) : "v"(p) : "memory");
  return r;
}

#define GLL16(gsrc, ldst) \
  __builtin_amdgcn_global_load_lds((const __attribute__((address_space(1))) void*)(gsrc), \
                                   (__attribute__((address_space(3))) void*)(ldst), 16, 0, 0)

// ---------------- fused prepass: weights->bf16 + biasT(flipped) + x transpose -------
__global__ __launch_bounds__(256) void prep_all(
    const float* __restrict__ x,
    const float* __restrict__ Wq, const float* __restrict__ bq,
    const float* __restrict__ Wkv, const float* __restrict__ bkv,
    const float* __restrict__ Wproj, const float* __restrict__ bproj,
    const float* __restrict__ gamma, const float* __restrict__ bias_table,
    u16* __restrict__ wqkv, u16* __restrict__ wp,
    float* __restrict__ bqkv, float* __restrict__ bp, float* __restrict__ biasT,
    u16* __restrict__ xT)
{
  __shared__ float tile[32][65];
  const int bid = blockIdx.x;
  const int tid = threadIdx.x;
  if (bid < 256) {   // ---- weights part ----
    const int total = W1SZ + W2SZ + QKV_M + MID + NBIAS * NHEADS;
    for (int i = bid * 256 + tid; i < total; i += 256 * 256) {
      if (i < W1SZ) {
        const int m = i / CIN;
        const float v = (m < MID) ? Wq[i] * QSCALE : Wkv[i - W2SZ];
        wqkv[i] = f2bf(v);
      } else if (i < W1SZ + W2SZ) {
        const int j = i - W1SZ;
        const int o = j / MID;
        wp[j] = f2bf(Wproj[j] * gamma[o]);
      } else if (i < W1SZ + W2SZ + QKV_M) {
        const int m = i - W1SZ - W2SZ;
        bqkv[m] = (m < MID) ? bq[m] * QSCALE : bkv[m - MID];
      } else if (i < W1SZ + W2SZ + QKV_M + MID) {
        const int o = i - W1SZ - W2SZ - QKV_M;
        bp[o] = bproj[o] * gamma[o];
      } else {
        const int j = i - (W1SZ + W2SZ + QKV_M + MID);
        const int h = j / NBIAS, r = j - h * NBIAS;
        biasT[j] = bias_table[(3024 - r) * NHEADS + h] * LOG2E;
      }
    }
    return;
  }
  // ---- x transpose part: [B][C][N] f32 -> [B][N][C] bf16, 32c x 64n tiles ----
  const int tix = bid - 256;            // 0..2495 = 13 nt * 12 ct * 16 b
  const int nt = tix % 13;
  const int rem = tix / 13;
  const int ct = rem % 12, b = rem / 12;
  const int n0 = nt * 64, c0 = ct * 32;
  #pragma unroll
  for (int p = 0; p < 2; ++p) {
    const int r = p * 16 + (tid >> 4);
    const int cc = (tid & 15) * 4;
    int n = n0 + cc; if (n > NPIX - 4) n = NPIX - 4;
    const float4 v = *(const float4*)(x + ((size_t)b * CIN + c0 + r) * NPIX + n);
    tile[r][cc + 0] = v.x; tile[r][cc + 1] = v.y;
    tile[r][cc + 2] = v.z; tile[r][cc + 3] = v.w;
  }
  __syncthreads();
  const int n_l = tid >> 2, cq = tid & 3;
  const int n = n0 + n_l;
  if (n < NPIX) {
    float f[8];
    #pragma unroll
    for (int e = 0; e < 8; ++e) f[e] = tile[cq * 8 + e][n_l];
    union { u32 u[4]; bf16x8 v; } pk;
    pk.u[0] = cvtpk_bf16(f[0], f[1]);
    pk.u[1] = cvtpk_bf16(f[2], f[3]);
    pk.u[2] = cvtpk_bf16(f[4], f[5]);
    pk.u[3] = cvtpk_bf16(f[6], f[7]);
    *(bf16x8*)(xT + ((size_t)b * NPIX + n) * CIN + c0 + cq * 8) = pk.v;
  }
}

// ---------------- QKV GEMM: dual-batch per block, double-buffer (R12) ---------------
__global__ __launch_bounds__(256) void qkv_gemm(
    const u16* __restrict__ wqkv, const float* __restrict__ bqkv,
    const u16* __restrict__ xT,
    u16* __restrict__ q_s, u16* __restrict__ k_s, u16* __restrict__ vt)
{
  __shared__ u16 As[2][128 * 32];      // 64B rows, XOR chunk swizzle key=(row>>1)&3
  __shared__ u16 Bs[2][2][64 * 32];    // [buf][batch]
  // 936 blocks = 8 xcd (batch-pair) * 117 (9 mt * 13 nt)
  const int id = blockIdx.x;
  const int xc = id & 7, s0 = id >> 3;
  const int b0 = xc * 2;
  const int m0 = (s0 % 9) * 128;
  const int n0 = (s0 / 9) * 64;
  const int tid = threadIdx.x, l = tid & 63, w = tid >> 6;
  const int wm = (w & 1) * 64, wn = (w >> 1) * 32;

  auto stage = [&](int kt, int buf) {
    #pragma unroll
    for (int s = 0; s < 2; ++s) {   // A: 8KB
      const int o = w * 2048 + s * 1024 + l * 16;
      const int row = o >> 6;
      const int c = ((o >> 4) & 3) ^ ((row >> 1) & 3);
      GLL16(wqkv + (size_t)(m0 + row) * CIN + kt * 32 + c * 8,
            (char*)As[buf] + w * 2048 + s * 1024);
    }
    const int o = w * 1024 + l * 16;
    const int row = o >> 6;
    const int c = ((o >> 4) & 3) ^ ((row >> 1) & 3);
    int nr = n0 + row; nr = nr > NPIX - 1 ? NPIX - 1 : nr;
    #pragma unroll
    for (int bi = 0; bi < 2; ++bi)
      GLL16(xT + ((size_t)(b0 + bi) * NPIX + nr) * CIN + kt * 32 + c * 8,
            (char*)Bs[buf][bi] + w * 1024);
  };

  const f32x4 vzero = {0.f, 0.f, 0.f, 0.f};
  f32x4 acc[2][4][2];
  #pragma unroll
  for (int bi = 0; bi < 2; ++bi)
    #pragma unroll
    for (int mi = 0; mi < 4; ++mi)
      #pragma unroll
      for (int ni = 0; ni < 2; ++ni) acc[bi][mi][ni] = vzero;

  stage(0, 0);
  for (int kt = 0; kt < 12; ++kt) {
    const int buf = kt & 1;
    __syncthreads();                 // drains vmcnt: buf ready; prev readers done
    if (kt < 11) stage(kt + 1, buf ^ 1);
    bf16x8 af[4], bfr[2][2];
    #pragma unroll
    for (int mi = 0; mi < 4; ++mi) {
      const int row = wm + mi * 16 + (l & 15);
      const int byte = row * 64 + (((l >> 4) ^ ((row >> 1) & 3)) << 4);
      af[mi] = *(const bf16x8*)((const char*)As[buf] + byte);
    }
    #pragma unroll
    for (int ni = 0; ni < 2; ++ni) {
      const int row = wn + ni * 16 + (l & 15);
      const int byte = row * 64 + (((l >> 4) ^ ((row >> 1) & 3)) << 4);
      #pragma unroll
      for (int bi = 0; bi < 2; ++bi)
        bfr[bi][ni] = *(const bf16x8*)((const char*)Bs[buf][bi] + byte);
    }
    __builtin_amdgcn_s_setprio(1);
    #pragma unroll
    for (int mi = 0; mi < 4; ++mi)
      #pragma unroll
      for (int bi = 0; bi < 2; ++bi)
        #pragma unroll
        for (int ni = 0; ni < 2; ++ni)
          acc[bi][mi][ni] = __builtin_amdgcn_mfma_f32_16x16x32_bf16(af[mi], bfr[bi][ni], acc[bi][mi][ni], 0, 0, 0);
    __builtin_amdgcn_s_setprio(0);
  }

  #pragma unroll
  for (int mi = 0; mi < 4; ++mi) {
    const int mrow0 = m0 + wm + mi * 16 + ((l >> 4) << 2);
    #pragma unroll
    for (int bi = 0; bi < 2; ++bi) {
      const int b = b0 + bi;
      #pragma unroll
      for (int ni = 0; ni < 2; ++ni) {
        const int n = n0 + wn + ni * 16 + (l & 15);
        if (n >= NPIX) continue;
        const float v0 = acc[bi][mi][ni][0] + bqkv[mrow0 + 0];
        const float v1 = acc[bi][mi][ni][1] + bqkv[mrow0 + 1];
        const float v2 = acc[bi][mi][ni][2] + bqkv[mrow0 + 2];
        const float v3 = acc[bi][mi][ni][3] + bqkv[mrow0 + 3];
        if (mrow0 < MID) {
          const int h = mrow0 >> 5, d = mrow0 & 31;
          ush4 pk; pk[0] = f2bf(v0); pk[1] = f2bf(v1); pk[2] = f2bf(v2); pk[3] = f2bf(v3);
          *(ush4*)(q_s + (((size_t)b * NHEADS + h) * NPIX + n) * HDIM + d) = pk;
        } else if (mrow0 < 2 * MID) {
          const int m2 = mrow0 - MID, h = m2 >> 5, d = m2 & 31;
          ush4 pk; pk[0] = f2bf(v0); pk[1] = f2bf(v1); pk[2] = f2bf(v2); pk[3] = f2bf(v3);
          *(ush4*)(k_s + (((size_t)b * NHEADS + h) * NPIX + n) * HDIM + d) = pk;
        } else {
          const int m2 = mrow0 - 2 * MID, h = m2 >> 5, d = m2 & 31;
          u16* p = vt + (((size_t)b * NHEADS + h) * HDIM + d) * NPIX + n;
          p[0] = f2bf(v0); p[NPIX] = f2bf(v1); p[2 * NPIX] = f2bf(v2); p[3 * NPIX] = f2bf(v3);
        }
      }
    }
  }
}

// ------- flash attention: 8 waves share K/V staging; R5 per-wave protocol verbatim --
__global__ __launch_bounds__(512) void attn(
    const u16* __restrict__ q_s, const u16* __restrict__ k_s, const u16* __restrict__ vt,
    const float* __restrict__ biasT, u16* __restrict__ oTb)
{
  __shared__ u16 Ks[2][64 * 32];   // [kv][d], 64B rows, key=(row>>1)&3   (8KB)
  __shared__ u16 Vs[2][32 * 64];   // [d][kv], 128B rows, key=row&7       (8KB)
  __shared__ u16 Ps[8][16 * 64];   // per-wave P, conflict-free swizzle   (16KB)
  // XCD swizzle: 1344 blocks = 8 xcd * 24 grp * 7 qt; same (b,h) -> same XCD
  const int id = blockIdx.x;
  const int xc = id & 7, s0i = id >> 3;
  const int grp = s0i / 7, qt = s0i - grp * 7;
  const int bh = grp * 8 + xc;
  const int h = bh % NHEADS, b = bh / NHEADS;
  const int tid = threadIdx.x, l = tid & 63, w = tid >> 6;
  const int g = l >> 4, qr = l & 15;
  const int qbase = qt * 128 + w * 16;
  const float* biasTh = biasT + h * NBIAS;

  int qrow = qbase + qr; qrow = qrow > NPIX - 1 ? NPIX - 1 : qrow;
  const bf16x8 qf = gload16b(q_s + ((size_t)bh * NPIX + qrow) * HDIM + g * 8);  // vmcnt+1

  const int yi = (qrow * 2341) >> 16;          // qrow / 28
  const int fbase = 1512 - qrow - 27 * yi;     // flipped-table base

  // P LDS addresses: chunk key + half swizzle -> conflict-free writes AND reads
  const int key = (qr & 7) ^ ((qr & 8) >> 1);
  const int hsw = qr >> 3;
  int addrW[4];
  #pragma unroll
  for (int nf = 0; nf < 4; ++nf)
    addrW[nf] = qr * 128 + ((((nf << 1) + (g >> 1)) ^ key) << 4) + (((g & 1) ^ hsw) << 3);
  int addrR0[2], addrR1[2];
  #pragma unroll
  for (int kk = 0; kk < 2; ++kk) {
    const int cb = qr * 128 + (((kk * 4 + g) ^ key) << 4);
    addrR0[kk] = cb + (hsw << 3);
    addrR1[kk] = cb + ((1 ^ hsw) << 3);
  }

  // stage roles: waves 0-3 stage K (4KB), waves 4-7 stage V (4KB); 1 GLL16/thread
  const u16* sptr;    // per-tile source, advances by sstep u16 per tile
  int sstep;
  const u16* sptr12;  // pre-clamped tail source
  if (w < 4) {
    const int o = w * 1024 + l * 16;
    const int row = o >> 6;
    const int c = ((o >> 4) & 3) ^ ((row >> 1) & 3);
    sptr = k_s + ((size_t)bh * NPIX + row) * HDIM + c * 8;
    sstep = 64 * HDIM;
    int r12 = 768 + row; r12 = r12 > NPIX - 1 ? NPIX - 1 : r12;
    sptr12 = k_s + ((size_t)bh * NPIX + r12) * HDIM + c * 8;
  } else {
    const int o = (w - 4) * 1024 + l * 16;
    const int d = o >> 7;
    const int c = ((o >> 4) & 7) ^ (d & 7);
    sptr = vt + ((size_t)bh * HDIM + d) * NPIX + c * 8;
    sstep = 64;
    int c12 = 768 + c * 8; c12 = c12 > NPIX - 8 ? NPIX - 8 : c12;
    sptr12 = vt + ((size_t)bh * HDIM + d) * NPIX + c12;
  }
  auto stage = [&](int t, int buf) {
    char* dst = (w < 4) ? (char*)Ks[buf] + w * 1024 : (char*)Vs[buf] + (w - 4) * 1024;
    const u16* src = (t < 12) ? sptr + (size_t)t * sstep : sptr12;
    GLL16(src, dst);
  };

  char* PsW = (char*)Ps[w];
  const f32x4 vzero = {0.f, 0.f, 0.f, 0.f};
  f32x4 oacc[2]; oacc[0] = vzero; oacc[1] = vzero;
  float lsum = 0.f;

  stage(0, 0);                              // queue: [qf, stage0] = 2

  for (int t = 0; t < 12; ++t) {
    const int kv0 = t * 64;
    f32x4 bfrag[4];
    #pragma unroll
    for (int nf = 0; nf < 4; ++nf) {        // 4 bias loads (rows i..i+3, same j)
      const int j4 = kv0 + nf * 16 + g * 4;
      const int yj = (j4 * 2341) >> 16;
      const int idx = fbase + j4 + 27 * yj;
      bfrag[nf] = gload16f(biasTh + idx);
    }
    asm volatile("s_waitcnt vmcnt(4)" ::: "memory");  // my stage(t) [+qf at t=0] done
    __builtin_amdgcn_s_barrier();                      // all waves' stage(t) done
    stage(t + 1, (t + 1) & 1);                         // 1 GLL in flight
    asm volatile("s_waitcnt vmcnt(1)" ::: "memory");  // bias done; stage(t+1) flying
    __builtin_amdgcn_sched_barrier(0);

    const char* KsB = (const char*)Ks[t & 1];
    const char* VsB = (const char*)Vs[t & 1];
    bf16x8 kf[4];
    #pragma unroll
    for (int nf = 0; nf < 4; ++nf) {
      const int row = nf * 16 + qr;
      const int byte = row * 64 + ((g ^ ((row >> 1) & 3)) << 4);
      kf[nf] = *(const bf16x8*)(KsB + byte);
    }
    f32x4 s[4];
    __builtin_amdgcn_s_setprio(1);
    #pragma unroll
    for (int nf = 0; nf < 4; ++nf)
      s[nf] = __builtin_amdgcn_mfma_f32_16x16x32_bf16(kf[nf], qf, bfrag[nf], 0, 0, 0);
    __builtin_amdgcn_s_setprio(0);

    #pragma unroll
    for (int nf = 0; nf < 4; ++nf) {
      const float p0 = __builtin_amdgcn_exp2f(s[nf][0]);
      const float p1 = __builtin_amdgcn_exp2f(s[nf][1]);
      const float p2 = __builtin_amdgcn_exp2f(s[nf][2]);
      const float p3 = __builtin_amdgcn_exp2f(s[nf][3]);
      lsum += (p0 + p1) + (p2 + p3);
      u32x2 wpair;
      wpair[0] = cvtpk_bf16(p0, p1);
      wpair[1] = cvtpk_bf16(p2, p3);
      *(u32x2*)(PsW + addrW[nf]) = wpair;
    }

    __builtin_amdgcn_s_setprio(1);
    #pragma unroll
    for (int kk = 0; kk < 2; ++kk) {
      union { u32x2 u2[2]; bf16x8 v8; } pau;
      pau.u2[0] = *(const u32x2*)(PsW + addrR0[kk]);
      pau.u2[1] = *(const u32x2*)(PsW + addrR1[kk]);
      #pragma unroll
      for (int nf2 = 0; nf2 < 2; ++nf2) {
        const int d = nf2 * 16 + qr;
        const int vbyte = d * 128 + (((kk * 4 + g) ^ (d & 7)) << 4);
        const bf16x8 vb = *(const bf16x8*)(VsB + vbyte);
        oacc[nf2] = __builtin_amdgcn_mfma_f32_16x16x32_bf16(pau.v8, vb, oacc[nf2], 0, 0, 0);
      }
    }
    __builtin_amdgcn_s_setprio(0);
  }

  // ---- peeled tail t=12: kv 768..783 valid (exactly nf=0); buf 0 ----
  {
    const int j4 = 768 + g * 4;
    const int yj = (j4 * 2341) >> 16;
    const int idx = fbase + j4 + 27 * yj;
    const f32x4 bf0 = gload16f(biasTh + idx);
    asm volatile("s_waitcnt vmcnt(1)" ::: "memory");  // stage(12) done; bf0 flying
    __builtin_amdgcn_s_barrier();
    asm volatile("s_waitcnt vmcnt(0)" ::: "memory");  // bias done
    __builtin_amdgcn_sched_barrier(0);

    const char* KsB = (const char*)Ks[0];
    const char* VsB = (const char*)Vs[0];
    const int byte = qr * 64 + ((g ^ ((qr >> 1) & 3)) << 4);
    const bf16x8 kf = *(const bf16x8*)(KsB + byte);
    const f32x4 s0 = __builtin_amdgcn_mfma_f32_16x16x32_bf16(kf, qf, bf0, 0, 0, 0);
    const float p0 = __builtin_amdgcn_exp2f(s0[0]);
    const float p1 = __builtin_amdgcn_exp2f(s0[1]);
    const float p2 = __builtin_amdgcn_exp2f(s0[2]);
    const float p3 = __builtin_amdgcn_exp2f(s0[3]);
    lsum += (p0 + p1) + (p2 + p3);
    u32x2 wpair;
    wpair[0] = cvtpk_bf16(p0, p1);
    wpair[1] = cvtpk_bf16(p2, p3);
    *(u32x2*)(PsW + addrW[0]) = wpair;
    const u32x2 zz = {0u, 0u};
    *(u32x2*)(PsW + addrW[1]) = zz;
    *(u32x2*)(PsW + addrW[2]) = zz;
    *(u32x2*)(PsW + addrW[3]) = zz;

    __builtin_amdgcn_s_setprio(1);
    #pragma unroll
    for (int kk = 0; kk < 2; ++kk) {
      union { u32x2 u2[2]; bf16x8 v8; } pau;
      pau.u2[0] = *(const u32x2*)(PsW + addrR0[kk]);
      pau.u2[1] = *(const u32x2*)(PsW + addrR1[kk]);
      #pragma unroll
      for (int nf2 = 0; nf2 < 2; ++nf2) {
        const int d = nf2 * 16 + qr;
        const int vbyte = d * 128 + (((kk * 4 + g) ^ (d & 7)) << 4);
        const bf16x8 vb = *(const bf16x8*)(VsB + vbyte);
        oacc[nf2] = __builtin_amdgcn_mfma_f32_16x16x32_bf16(pau.v8, vb, oacc[nf2], 0, 0, 0);
      }
    }
    __builtin_amdgcn_s_setprio(0);
  }

  // row-sum: combine the 4 kv-quarters
  lsum += __shfl_xor(lsum, 16, 64);
  lsum += __shfl_xor(lsum, 32, 64);

  #pragma unroll
  for (int jr = 0; jr < 4; ++jr) {
    const int i = qbase + g * 4 + jr;
    const float rsum = __shfl(lsum, g * 4 + jr, 64);
    if (i >= NPIX) continue;
    const float inv = 1.f / rsum;
    #pragma unroll
    for (int nf2 = 0; nf2 < 2; ++nf2) {
      const int m = h * HDIM + nf2 * 16 + qr;
      oTb[((size_t)b * NPIX + i) * MID + m] = f2bf(oacc[nf2][jr] * inv);
    }
  }
}

// ---------------- output proj: dual-batch bf16 GEMM, double-buffer (R12) ------------
__global__ __launch_bounds__(256) void proj_gemm(
    const u16* __restrict__ wp, const float* __restrict__ bp,
    const u16* __restrict__ oTb, float* __restrict__ out)
{
  __shared__ u16 Ah[2][128 * 32];
  __shared__ u16 Bh[2][2][64 * 32];
  // 312 blocks = 8 xcd (batch-pair) * 39 (3 mt * 13 nt)
  const int id = blockIdx.x;
  const int xc = id & 7, s0 = id >> 3;
  const int b0 = xc * 2;
  const int m0 = (s0 % 3) * 128;
  const int n0 = (s0 / 3) * 64;
  const int tid = threadIdx.x, l = tid & 63, w = tid >> 6;
  const int wm = (w & 1) * 64, wn = (w >> 1) * 32;

  auto stage = [&](int kt, int buf) {
    #pragma unroll
    for (int s = 0; s < 2; ++s) {
      const int o = w * 2048 + s * 1024 + l * 16;
      const int row = o >> 6;
      const int c = ((o >> 4) & 3) ^ ((row >> 1) & 3);
      GLL16(wp + (size_t)(m0 + row) * MID + kt * 32 + c * 8,
            (char*)Ah[buf] + w * 2048 + s * 1024);
    }
    const int o = w * 1024 + l * 16;
    const int row = o >> 6;
    const int c = ((o >> 4) & 3) ^ ((row >> 1) & 3);
    int nr = n0 + row; nr = nr > NPIX - 1 ? NPIX - 1 : nr;
    #pragma unroll
    for (int bi = 0; bi < 2; ++bi)
      GLL16(oTb + ((size_t)(b0 + bi) * NPIX + nr) * MID + kt * 32 + c * 8,
            (char*)Bh[buf][bi] + w * 1024);
  };

  const f32x4 vzero = {0.f, 0.f, 0.f, 0.f};
  f32x4 acc[2][4][2];
  #pragma unroll
  for (int bi = 0; bi < 2; ++bi)
    #pragma unroll
    for (int mi = 0; mi < 4; ++mi)
      #pragma unroll
      for (int ni = 0; ni < 2; ++ni) acc[bi][mi][ni] = vzero;

  stage(0, 0);
  for (int kt = 0; kt < 12; ++kt) {
    const int buf = kt & 1;
    __syncthreads();
    if (kt < 11) stage(kt + 1, buf ^ 1);
    bf16x8 ah[4], bfr[2][2];
    #pragma unroll
    for (int mi = 0; mi < 4; ++mi) {
      const int row = wm + mi * 16 + (l & 15);
      const int byte = row * 64 + (((l >> 4) ^ ((row >> 1) & 3)) << 4);
      ah[mi] = *(const bf16x8*)((const char*)Ah[buf] + byte);
    }
    #pragma unroll
    for (int ni = 0; ni < 2; ++ni) {
      const int row = wn + ni * 16 + (l & 15);
      const int byte = row * 64 + (((l >> 4) ^ ((row >> 1) & 3)) << 4);
      #pragma unroll
      for (int bi = 0; bi < 2; ++bi)
        bfr[bi][ni] = *(const bf16x8*)((const char*)Bh[buf][bi] + byte);
    }
    __builtin_amdgcn_s_setprio(1);
    #pragma unroll
    for (int mi = 0; mi < 4; ++mi)
      #pragma unroll
      for (int bi = 0; bi < 2; ++bi)
        #pragma unroll
        for (int ni = 0; ni < 2; ++ni)
          acc[bi][mi][ni] = __builtin_amdgcn_mfma_f32_16x16x32_bf16(ah[mi], bfr[bi][ni], acc[bi][mi][ni], 0, 0, 0);
    __builtin_amdgcn_s_setprio(0);
  }

  #pragma unroll
  for (int mi = 0; mi < 4; ++mi) {
    const int o0 = m0 + wm + mi * 16 + ((l >> 4) << 2);
    #pragma unroll
    for (int bi = 0; bi < 2; ++bi) {
      const int b = b0 + bi;
      #pragma unroll
      for (int ni = 0; ni < 2; ++ni) {
        const int n = n0 + wn + ni * 16 + (l & 15);
        if (n >= NPIX) continue;
        #pragma unroll
        for (int jr = 0; jr < 4; ++jr)
          out[((size_t)b * MID + o0 + jr) * NPIX + n] = acc[bi][mi][ni][jr] + bp[o0 + jr];
      }
    }
  }
}

extern "C" void kernel_launch(void* const* d_in, const int* in_sizes, int n_in,
                              void* d_out, int out_size, void* d_ws, size_t ws_size,
                              hipStream_t stream) {
  const float* x          = (const float*)d_in[0];
  const float* Wq         = (const float*)d_in[1];
  const float* bq         = (const float*)d_in[2];
  const float* Wkv        = (const float*)d_in[3];
  const float* bkv        = (const float*)d_in[4];
  const float* bias_table = (const float*)d_in[5];
  const float* Wproj      = (const float*)d_in[6];
  const float* bproj      = (const float*)d_in[7];
  const float* gamma      = (const float*)d_in[8];

  char* ws = (char*)d_ws;
  u16*   xT    = (u16*)(ws + 0);          //  9,633,792 B
  u16*   wqkv  = (u16*)(ws + 9633792);    //    884,736 B
  u16*   wp    = (u16*)(ws + 10518528);   //    294,912 B
  float* bqkv  = (float*)(ws + 10813440); //      4,608 B
  float* bp    = (float*)(ws + 10818048); //      1,536 B
  float* biasT = (float*)(ws + 10819584); //    145,200 B (pad to 145,408)
  u16*   q_s   = (u16*)(ws + 10964992);   //  9,633,792 B
  u16*   k_s   = (u16*)(ws + 20598784);   //  9,633,792 B
  u16*   vt    = (u16*)(ws + 30232576);   //  9,633,792 B
  u16*   oTb   = (u16*)(ws + 39866368);   //  9,633,792 B  (total ~49.5 MB)
  float* out   = (float*)d_out;

  prep_all<<<dim3(2752), dim3(256), 0, stream>>>(x, Wq, bq, Wkv, bkv, Wproj, bproj, gamma,
                                                 bias_table, wqkv, wp, bqkv, bp, biasT, xT);
  qkv_gemm<<<dim3(936), dim3(256), 0, stream>>>(wqkv, bqkv, xT, q_s, k_s, vt);
  attn<<<dim3(1344), dim3(512), 0, stream>>>(q_s, k_s, vt, biasT, oTb);
  proj_gemm<<<dim3(312), dim3(256), 0, stream>>>(wp, bp, oTb, out);
}

// Round 16
// 96.161 us; speedup vs baseline: 1.0027x; 1.0027x over previous
//
#include <hip/hip_runtime.h>
#include <hip/hip_bf16.h>

#define NPIX   784
#define CIN    384
#define NHEADS 12
#define HDIM   32
#define MID    384
#define QKV_M  1152
#define LOG2E  1.4426950408889634f
#define QSCALE (0.17677669529663687f * 1.4426950408889634f)
#define W1SZ   442368   // 1152*384
#define W2SZ   147456   // 384*384
#define NBIAS  3025     // 55*55

typedef __attribute__((ext_vector_type(8))) short bf16x8;
typedef __attribute__((ext_vector_type(4))) float f32x4;
typedef __attribute__((ext_vector_type(4))) unsigned short ush4;
typedef __attribute__((ext_vector_type(2))) unsigned int u32x2;
typedef unsigned short u16;
typedef unsigned int u32;

__device__ __forceinline__ u16 f2bf(float f) {
  union { float f; u32 u; } v; v.f = f;
  u32 u = v.u;
  u += 0x7fffu + ((u >> 16) & 1u);
  return (u16)(u >> 16);
}
__device__ __forceinline__ u32 cvtpk_bf16(float lo, float hi) {
  u32 r;
  asm("v_cvt_pk_bf16_f32 %0, %1, %2" : "=v"(r) : "v"(lo), "v"(hi));
  return r;
}
// untracked global loads (vmcnt managed manually by the attn protocol)
__device__ __forceinline__ f32x4 gload16f(const float* p) {
  f32x4 r;
  asm volatile("global_load_dwordx4 %0, %1, off" : "=v"(r) : "v"(p) : "memory");
  return r;
}
__device__ __forceinline__ bf16x8 gload16b(const u16* p) {
  bf16x8 r;
  asm volatile("global_load_dwordx4 %0, %1, off" : "=v"(r) : "v"(p) : "memory");
  return r;
}

#define GLL16(gsrc, ldst) \
  __builtin_amdgcn_global_load_lds((const __attribute__((address_space(1))) void*)(gsrc), \
                                   (__attribute__((address_space(3))) void*)(ldst), 16, 0, 0)

// ---------------- fused prepass: weights->bf16 + biasT(flipped) + x transpose -------
__global__ __launch_bounds__(256) void prep_all(
    const float* __restrict__ x,
    const float* __restrict__ Wq, const float* __restrict__ bq,
    const float* __restrict__ Wkv, const float* __restrict__ bkv,
    const float* __restrict__ Wproj, const float* __restrict__ bproj,
    const float* __restrict__ gamma, const float* __restrict__ bias_table,
    u16* __restrict__ wqkv, u16* __restrict__ wp,
    float* __restrict__ bqkv, float* __restrict__ bp, float* __restrict__ biasT,
    u16* __restrict__ xT)
{
  __shared__ float tile[32][65];
  const int bid = blockIdx.x;
  const int tid = threadIdx.x;
  if (bid < 256) {   // ---- weights part ----
    const int total = W1SZ + W2SZ + QKV_M + MID + NBIAS * NHEADS;
    for (int i = bid * 256 + tid; i < total; i += 256 * 256) {
      if (i < W1SZ) {
        const int m = i / CIN;
        const float v = (m < MID) ? Wq[i] * QSCALE : Wkv[i - W2SZ];
        wqkv[i] = f2bf(v);
      } else if (i < W1SZ + W2SZ) {
        const int j = i - W1SZ;
        const int o = j / MID;
        wp[j] = f2bf(Wproj[j] * gamma[o]);
      } else if (i < W1SZ + W2SZ + QKV_M) {
        const int m = i - W1SZ - W2SZ;
        bqkv[m] = (m < MID) ? bq[m] * QSCALE : bkv[m - MID];
      } else if (i < W1SZ + W2SZ + QKV_M + MID) {
        const int o = i - W1SZ - W2SZ - QKV_M;
        bp[o] = bproj[o] * gamma[o];
      } else {
        const int j = i - (W1SZ + W2SZ + QKV_M + MID);
        const int h = j / NBIAS, r = j - h * NBIAS;
        biasT[j] = bias_table[(3024 - r) * NHEADS + h] * LOG2E;
      }
    }
    return;
  }
  // ---- x transpose part: [B][C][N] f32 -> [B][N][C] bf16, 32c x 64n tiles ----
  const int tix = bid - 256;            // 0..2495 = 13 nt * 12 ct * 16 b
  const int nt = tix % 13;
  const int rem = tix / 13;
  const int ct = rem % 12, b = rem / 12;
  const int n0 = nt * 64, c0 = ct * 32;
  #pragma unroll
  for (int p = 0; p < 2; ++p) {
    const int r = p * 16 + (tid >> 4);
    const int cc = (tid & 15) * 4;
    int n = n0 + cc; if (n > NPIX - 4) n = NPIX - 4;
    const float4 v = *(const float4*)(x + ((size_t)b * CIN + c0 + r) * NPIX + n);
    tile[r][cc + 0] = v.x; tile[r][cc + 1] = v.y;
    tile[r][cc + 2] = v.z; tile[r][cc + 3] = v.w;
  }
  __syncthreads();
  const int n_l = tid >> 2, cq = tid & 3;
  const int n = n0 + n_l;
  if (n < NPIX) {
    float f[8];
    #pragma unroll
    for (int e = 0; e < 8; ++e) f[e] = tile[cq * 8 + e][n_l];
    union { u32 u[4]; bf16x8 v; } pk;
    pk.u[0] = cvtpk_bf16(f[0], f[1]);
    pk.u[1] = cvtpk_bf16(f[2], f[3]);
    pk.u[2] = cvtpk_bf16(f[4], f[5]);
    pk.u[3] = cvtpk_bf16(f[6], f[7]);
    *(bf16x8*)(xT + ((size_t)b * NPIX + n) * CIN + c0 + cq * 8) = pk.v;
  }
}

// ---------------- QKV GEMM: dual-batch per block, double-buffer (R12) ---------------
__global__ __launch_bounds__(256) void qkv_gemm(
    const u16* __restrict__ wqkv, const float* __restrict__ bqkv,
    const u16* __restrict__ xT,
    u16* __restrict__ q_s, u16* __restrict__ k_s, u16* __restrict__ vt)
{
  __shared__ u16 As[2][128 * 32];      // 64B rows, XOR chunk swizzle key=(row>>1)&3
  __shared__ u16 Bs[2][2][64 * 32];    // [buf][batch]
  // 936 blocks = 8 xcd (batch-pair) * 117 (9 mt * 13 nt)
  const int id = blockIdx.x;
  const int xc = id & 7, s0 = id >> 3;
  const int b0 = xc * 2;
  const int m0 = (s0 % 9) * 128;
  const int n0 = (s0 / 9) * 64;
  const int tid = threadIdx.x, l = tid & 63, w = tid >> 6;
  const int wm = (w & 1) * 64, wn = (w >> 1) * 32;

  auto stage = [&](int kt, int buf) {
    #pragma unroll
    for (int s = 0; s < 2; ++s) {   // A: 8KB
      const int o = w * 2048 + s * 1024 + l * 16;
      const int row = o >> 6;
      const int c = ((o >> 4) & 3) ^ ((row >> 1) & 3);
      GLL16(wqkv + (size_t)(m0 + row) * CIN + kt * 32 + c * 8,
            (char*)As[buf] + w * 2048 + s * 1024);
    }
    const int o = w * 1024 + l * 16;
    const int row = o >> 6;
    const int c = ((o >> 4) & 3) ^ ((row >> 1) & 3);
    int nr = n0 + row; nr = nr > NPIX - 1 ? NPIX - 1 : nr;
    #pragma unroll
    for (int bi = 0; bi < 2; ++bi)
      GLL16(xT + ((size_t)(b0 + bi) * NPIX + nr) * CIN + kt * 32 + c * 8,
            (char*)Bs[buf][bi] + w * 1024);
  };

  const f32x4 vzero = {0.f, 0.f, 0.f, 0.f};
  f32x4 acc[2][4][2];
  #pragma unroll
  for (int bi = 0; bi < 2; ++bi)
    #pragma unroll
    for (int mi = 0; mi < 4; ++mi)
      #pragma unroll
      for (int ni = 0; ni < 2; ++ni) acc[bi][mi][ni] = vzero;

  stage(0, 0);
  for (int kt = 0; kt < 12; ++kt) {
    const int buf = kt & 1;
    __syncthreads();                 // drains vmcnt: buf ready; prev readers done
    if (kt < 11) stage(kt + 1, buf ^ 1);
    bf16x8 af[4], bfr[2][2];
    #pragma unroll
    for (int mi = 0; mi < 4; ++mi) {
      const int row = wm + mi * 16 + (l & 15);
      const int byte = row * 64 + (((l >> 4) ^ ((row >> 1) & 3)) << 4);
      af[mi] = *(const bf16x8*)((const char*)As[buf] + byte);
    }
    #pragma unroll
    for (int ni = 0; ni < 2; ++ni) {
      const int row = wn + ni * 16 + (l & 15);
      const int byte = row * 64 + (((l >> 4) ^ ((row >> 1) & 3)) << 4);
      #pragma unroll
      for (int bi = 0; bi < 2; ++bi)
        bfr[bi][ni] = *(const bf16x8*)((const char*)Bs[buf][bi] + byte);
    }
    __builtin_amdgcn_s_setprio(1);
    #pragma unroll
    for (int mi = 0; mi < 4; ++mi)
      #pragma unroll
      for (int bi = 0; bi < 2; ++bi)
        #pragma unroll
        for (int ni = 0; ni < 2; ++ni)
          acc[bi][mi][ni] = __builtin_amdgcn_mfma_f32_16x16x32_bf16(af[mi], bfr[bi][ni], acc[bi][mi][ni], 0, 0, 0);
    __builtin_amdgcn_s_setprio(0);
  }

  #pragma unroll
  for (int mi = 0; mi < 4; ++mi) {
    const int mrow0 = m0 + wm + mi * 16 + ((l >> 4) << 2);
    #pragma unroll
    for (int bi = 0; bi < 2; ++bi) {
      const int b = b0 + bi;
      #pragma unroll
      for (int ni = 0; ni < 2; ++ni) {
        const int n = n0 + wn + ni * 16 + (l & 15);
        if (n >= NPIX) continue;
        const float v0 = acc[bi][mi][ni][0] + bqkv[mrow0 + 0];
        const float v1 = acc[bi][mi][ni][1] + bqkv[mrow0 + 1];
        const float v2 = acc[bi][mi][ni][2] + bqkv[mrow0 + 2];
        const float v3 = acc[bi][mi][ni][3] + bqkv[mrow0 + 3];
        if (mrow0 < MID) {
          const int h = mrow0 >> 5, d = mrow0 & 31;
          ush4 pk; pk[0] = f2bf(v0); pk[1] = f2bf(v1); pk[2] = f2bf(v2); pk[3] = f2bf(v3);
          *(ush4*)(q_s + (((size_t)b * NHEADS + h) * NPIX + n) * HDIM + d) = pk;
        } else if (mrow0 < 2 * MID) {
          const int m2 = mrow0 - MID, h = m2 >> 5, d = m2 & 31;
          ush4 pk; pk[0] = f2bf(v0); pk[1] = f2bf(v1); pk[2] = f2bf(v2); pk[3] = f2bf(v3);
          *(ush4*)(k_s + (((size_t)b * NHEADS + h) * NPIX + n) * HDIM + d) = pk;
        } else {
          const int m2 = mrow0 - 2 * MID, h = m2 >> 5, d = m2 & 31;
          u16* p = vt + (((size_t)b * NHEADS + h) * HDIM + d) * NPIX + n;
          p[0] = f2bf(v0); p[NPIX] = f2bf(v1); p[2 * NPIX] = f2bf(v2); p[3 * NPIX] = f2bf(v3);
        }
      }
    }
  }
}

// ---- flash attention: 7 waves x 16 q-rows (784 = 7*112 exact, zero waste) ----------
__global__ __launch_bounds__(448) void attn(
    const u16* __restrict__ q_s, const u16* __restrict__ k_s, const u16* __restrict__ vt,
    const float* __restrict__ biasT, u16* __restrict__ oTb)
{
  __shared__ u16 Ks[2][64 * 32];   // [kv][d], 64B rows, key=(row>>1)&3   (8KB)
  __shared__ u16 Vs[2][32 * 64];   // [d][kv], 128B rows, key=row&7       (8KB)
  __shared__ u16 Ps[7][16 * 64];   // per-wave P, conflict-free swizzle   (14KB)
  // XCD swizzle: 1344 blocks = 8 xcd * 24 grp * 7 qt; same (b,h) -> same XCD
  const int id = blockIdx.x;
  const int xc = id & 7, s0i = id >> 3;
  const int grp = s0i / 7, qt = s0i - grp * 7;
  const int bh = grp * 8 + xc;
  const int h = bh % NHEADS, b = bh / NHEADS;
  const int tid = threadIdx.x, l = tid & 63, w = tid >> 6;   // w = 0..6
  const int g = l >> 4, qr = l & 15;
  const int qbase = qt * 112 + w * 16;         // <= 768; qrow <= 783 always
  const float* biasTh = biasT + h * NBIAS;

  const int qrow = qbase + qr;                 // in-bounds by construction
  const bf16x8 qf = gload16b(q_s + ((size_t)bh * NPIX + qrow) * HDIM + g * 8);  // vmcnt+1

  const int yi = (qrow * 2341) >> 16;          // qrow / 28
  const int fbase = 1512 - qrow - 27 * yi;     // flipped-table base

  // P LDS addresses: chunk key + half swizzle -> conflict-free writes AND reads
  const int key = (qr & 7) ^ ((qr & 8) >> 1);
  const int hsw = qr >> 3;
  int addrW[4];
  #pragma unroll
  for (int nf = 0; nf < 4; ++nf)
    addrW[nf] = qr * 128 + ((((nf << 1) + (g >> 1)) ^ key) << 4) + (((g & 1) ^ hsw) << 3);
  int addrR0[2], addrR1[2];
  #pragma unroll
  for (int kk = 0; kk < 2; ++kk) {
    const int cb = qr * 128 + (((kk * 4 + g) ^ key) << 4);
    addrR0[kk] = cb + (hsw << 3);
    addrR1[kk] = cb + ((1 ^ hsw) << 3);
  }

  // staging: 8 x 1KB chunks (K:0-3, V:4-7) over 7 waves; wave 3 also does chunk 7
  // chunk w for all waves:
  const u16* sA; int stepA; const u16* sA12; int dofsA; bool dstKA;
  {
    const int ch = w;
    const int o = (ch < 4 ? ch : ch - 4) * 1024 + l * 16;
    if (ch < 4) {
      const int row = o >> 6;
      const int c = ((o >> 4) & 3) ^ ((row >> 1) & 3);
      sA = k_s + ((size_t)bh * NPIX + row) * HDIM + c * 8;
      stepA = 64 * HDIM;
      int r12 = 768 + row; r12 = r12 > NPIX - 1 ? NPIX - 1 : r12;
      sA12 = k_s + ((size_t)bh * NPIX + r12) * HDIM + c * 8;
      dofsA = ch * 1024; dstKA = true;
    } else {
      const int d = o >> 7;
      const int c = ((o >> 4) & 7) ^ (d & 7);
      sA = vt + ((size_t)bh * HDIM + d) * NPIX + c * 8;
      stepA = 64;
      int c12 = 768 + c * 8; c12 = c12 > NPIX - 8 ? NPIX - 8 : c12;
      sA12 = vt + ((size_t)bh * HDIM + d) * NPIX + c12;
      dofsA = (ch - 4) * 1024; dstKA = false;
    }
  }
  // chunk 7 (V chunk 3) — issued by wave 3 only:
  const u16* sB; const u16* sB12;
  {
    const int o = 3 * 1024 + l * 16;
    const int d = o >> 7;
    const int c = ((o >> 4) & 7) ^ (d & 7);
    sB = vt + ((size_t)bh * HDIM + d) * NPIX + c * 8;
    int c12 = 768 + c * 8; c12 = c12 > NPIX - 8 ? NPIX - 8 : c12;
    sB12 = vt + ((size_t)bh * HDIM + d) * NPIX + c12;
  }
  const bool dbl = (w == 3);

  auto stage = [&](int t, int buf) {
    char* dstA = (dstKA ? (char*)Ks[buf] : (char*)Vs[buf]) + dofsA;
    const u16* srcA = (t < 12) ? sA + (size_t)t * stepA : sA12;
    GLL16(srcA, dstA);
    if (dbl) {
      const u16* srcB = (t < 12) ? sB + (size_t)t * 64 : sB12;
      GLL16(srcB, (char*)Vs[buf] + 3 * 1024);
    }
  };

  char* PsW = (char*)Ps[w];
  const f32x4 vzero = {0.f, 0.f, 0.f, 0.f};
  f32x4 oacc[2]; oacc[0] = vzero; oacc[1] = vzero;
  float lsum = 0.f;

  stage(0, 0);                              // queue: [qf, stage0 x(1|2)]

  for (int t = 0; t < 12; ++t) {
    const int kv0 = t * 64;
    f32x4 bfrag[4];
    #pragma unroll
    for (int nf = 0; nf < 4; ++nf) {        // 4 bias loads (rows i..i+3, same j)
      const int j4 = kv0 + nf * 16 + g * 4;
      const int yj = (j4 * 2341) >> 16;
      const int idx = fbase + j4 + 27 * yj;
      bfrag[nf] = gload16f(biasTh + idx);
    }
    // biases are the newest 4 entries -> vmcnt(4) retires all my stage(t) GLLs (+qf at t=0)
    asm volatile("s_waitcnt vmcnt(4)" ::: "memory");
    __builtin_amdgcn_s_barrier();                      // all waves' stage(t) done
    stage(t + 1, (t + 1) & 1);                         // 1 (or 2) GLL in flight
    if (dbl) asm volatile("s_waitcnt vmcnt(2)" ::: "memory");  // bias done; stage(t+1) flying
    else     asm volatile("s_waitcnt vmcnt(1)" ::: "memory");
    __builtin_amdgcn_sched_barrier(0);

    const char* KsB = (const char*)Ks[t & 1];
    const char* VsB = (const char*)Vs[t & 1];
    bf16x8 kf[4];
    #pragma unroll
    for (int nf = 0; nf < 4; ++nf) {
      const int row = nf * 16 + qr;
      const int byte = row * 64 + ((g ^ ((row >> 1) & 3)) << 4);
      kf[nf] = *(const bf16x8*)(KsB + byte);
    }
    f32x4 s[4];
    __builtin_amdgcn_s_setprio(1);
    #pragma unroll
    for (int nf = 0; nf < 4; ++nf)
      s[nf] = __builtin_amdgcn_mfma_f32_16x16x32_bf16(kf[nf], qf, bfrag[nf], 0, 0, 0);
    __builtin_amdgcn_s_setprio(0);

    #pragma unroll
    for (int nf = 0; nf < 4; ++nf) {
      const float p0 = __builtin_amdgcn_exp2f(s[nf][0]);
      const float p1 = __builtin_amdgcn_exp2f(s[nf][1]);
      const float p2 = __builtin_amdgcn_exp2f(s[nf][2]);
      const float p3 = __builtin_amdgcn_exp2f(s[nf][3]);
      lsum += (p0 + p1) + (p2 + p3);
      u32x2 wpair;
      wpair[0] = cvtpk_bf16(p0, p1);
      wpair[1] = cvtpk_bf16(p2, p3);
      *(u32x2*)(PsW + addrW[nf]) = wpair;
    }

    __builtin_amdgcn_s_setprio(1);
    #pragma unroll
    for (int kk = 0; kk < 2; ++kk) {
      union { u32x2 u2[2]; bf16x8 v8; } pau;
      pau.u2[0] = *(const u32x2*)(PsW + addrR0[kk]);
      pau.u2[1] = *(const u32x2*)(PsW + addrR1[kk]);
      #pragma unroll
      for (int nf2 = 0; nf2 < 2; ++nf2) {
        const int d = nf2 * 16 + qr;
        const int vbyte = d * 128 + (((kk * 4 + g) ^ (d & 7)) << 4);
        const bf16x8 vb = *(const bf16x8*)(VsB + vbyte);
        oacc[nf2] = __builtin_amdgcn_mfma_f32_16x16x32_bf16(pau.v8, vb, oacc[nf2], 0, 0, 0);
      }
    }
    __builtin_amdgcn_s_setprio(0);
  }

  // ---- peeled tail t=12: kv 768..783 valid (exactly nf=0); buf 0 ----
  {
    const int j4 = 768 + g * 4;
    const int yj = (j4 * 2341) >> 16;
    const int idx = fbase + j4 + 27 * yj;
    const f32x4 bf0 = gload16f(biasTh + idx);
    asm volatile("s_waitcnt vmcnt(1)" ::: "memory");  // stage(12) done; bf0 flying
    __builtin_amdgcn_s_barrier();
    asm volatile("s_waitcnt vmcnt(0)" ::: "memory");  // bias done
    __builtin_amdgcn_sched_barrier(0);

    const char* KsB = (const char*)Ks[0];
    const char* VsB = (const char*)Vs[0];
    const int byte = qr * 64 + ((g ^ ((qr >> 1) & 3)) << 4);
    const bf16x8 kf = *(const bf16x8*)(KsB + byte);
    const f32x4 s0 = __builtin_amdgcn_mfma_f32_16x16x32_bf16(kf, qf, bf0, 0, 0, 0);
    const float p0 = __builtin_amdgcn_exp2f(s0[0]);
    const float p1 = __builtin_amdgcn_exp2f(s0[1]);
    const float p2 = __builtin_amdgcn_exp2f(s0[2]);
    const float p3 = __builtin_amdgcn_exp2f(s0[3]);
    lsum += (p0 + p1) + (p2 + p3);
    u32x2 wpair;
    wpair[0] = cvtpk_bf16(p0, p1);
    wpair[1] = cvtpk_bf16(p2, p3);
    *(u32x2*)(PsW + addrW[0]) = wpair;
    const u32x2 zz = {0u, 0u};
    *(u32x2*)(PsW + addrW[1]) = zz;
    *(u32x2*)(PsW + addrW[2]) = zz;
    *(u32x2*)(PsW + addrW[3]) = zz;

    __builtin_amdgcn_s_setprio(1);
    #pragma unroll
    for (int kk = 0; kk < 2; ++kk) {
      union { u32x2 u2[2]; bf16x8 v8; } pau;
      pau.u2[0] = *(const u32x2*)(PsW + addrR0[kk]);
      pau.u2[1] = *(const u32x2*)(PsW + addrR1[kk]);
      #pragma unroll
      for (int nf2 = 0; nf2 < 2; ++nf2) {
        const int d = nf2 * 16 + qr;
        const int vbyte = d * 128 + (((kk * 4 + g) ^ (d & 7)) << 4);
        const bf16x8 vb = *(const bf16x8*)(VsB + vbyte);
        oacc[nf2] = __builtin_amdgcn_mfma_f32_16x16x32_bf16(pau.v8, vb, oacc[nf2], 0, 0, 0);
      }
    }
    __builtin_amdgcn_s_setprio(0);
  }

  // row-sum: combine the 4 kv-quarters
  lsum += __shfl_xor(lsum, 16, 64);
  lsum += __shfl_xor(lsum, 32, 64);

  #pragma unroll
  for (int jr = 0; jr < 4; ++jr) {
    const int i = qbase + g * 4 + jr;       // <= 783 by construction
    const float rsum = __shfl(lsum, g * 4 + jr, 64);
    const float inv = 1.f / rsum;
    #pragma unroll
    for (int nf2 = 0; nf2 < 2; ++nf2) {
      const int m = h * HDIM + nf2 * 16 + qr;
      oTb[((size_t)b * NPIX + i) * MID + m] = f2bf(oacc[nf2][jr] * inv);
    }
  }
}

// ---------------- output proj: dual-batch bf16 GEMM, double-buffer (R12) ------------
__global__ __launch_bounds__(256) void proj_gemm(
    const u16* __restrict__ wp, const float* __restrict__ bp,
    const u16* __restrict__ oTb, float* __restrict__ out)
{
  __shared__ u16 Ah[2][128 * 32];
  __shared__ u16 Bh[2][2][64 * 32];
  // 312 blocks = 8 xcd (batch-pair) * 39 (3 mt * 13 nt)
  const int id = blockIdx.x;
  const int xc = id & 7, s0 = id >> 3;
  const int b0 = xc * 2;
  const int m0 = (s0 % 3) * 128;
  const int n0 = (s0 / 3) * 64;
  const int tid = threadIdx.x, l = tid & 63, w = tid >> 6;
  const int wm = (w & 1) * 64, wn = (w >> 1) * 32;

  auto stage = [&](int kt, int buf) {
    #pragma unroll
    for (int s = 0; s < 2; ++s) {
      const int o = w * 2048 + s * 1024 + l * 16;
      const int row = o >> 6;
      const int c = ((o >> 4) & 3) ^ ((row >> 1) & 3);
      GLL16(wp + (size_t)(m0 + row) * MID + kt * 32 + c * 8,
            (char*)Ah[buf] + w * 2048 + s * 1024);
    }
    const int o = w * 1024 + l * 16;
    const int row = o >> 6;
    const int c = ((o >> 4) & 3) ^ ((row >> 1) & 3);
    int nr = n0 + row; nr = nr > NPIX - 1 ? NPIX - 1 : nr;
    #pragma unroll
    for (int bi = 0; bi < 2; ++bi)
      GLL16(oTb + ((size_t)(b0 + bi) * NPIX + nr) * MID + kt * 32 + c * 8,
            (char*)Bh[buf][bi] + w * 1024);
  };

  const f32x4 vzero = {0.f, 0.f, 0.f, 0.f};
  f32x4 acc[2][4][2];
  #pragma unroll
  for (int bi = 0; bi < 2; ++bi)
    #pragma unroll
    for (int mi = 0; mi < 4; ++mi)
      #pragma unroll
      for (int ni = 0; ni < 2; ++ni) acc[bi][mi][ni] = vzero;

  stage(0, 0);
  for (int kt = 0; kt < 12; ++kt) {
    const int buf = kt & 1;
    __syncthreads();
    if (kt < 11) stage(kt + 1, buf ^ 1);
    bf16x8 ah[4], bfr[2][2];
    #pragma unroll
    for (int mi = 0; mi < 4; ++mi) {
      const int row = wm + mi * 16 + (l & 15);
      const int byte = row * 64 + (((l >> 4) ^ ((row >> 1) & 3)) << 4);
      ah[mi] = *(const bf16x8*)((const char*)Ah[buf] + byte);
    }
    #pragma unroll
    for (int ni = 0; ni < 2; ++ni) {
      const int row = wn + ni * 16 + (l & 15);
      const int byte = row * 64 + (((l >> 4) ^ ((row >> 1) & 3)) << 4);
      #pragma unroll
      for (int bi = 0; bi < 2; ++bi)
        bfr[bi][ni] = *(const bf16x8*)((const char*)Bh[buf][bi] + byte);
    }
    __builtin_amdgcn_s_setprio(1);
    #pragma unroll
    for (int mi = 0; mi < 4; ++mi)
      #pragma unroll
      for (int bi = 0; bi < 2; ++bi)
        #pragma unroll
        for (int ni = 0; ni < 2; ++ni)
          acc[bi][mi][ni] = __builtin_amdgcn_mfma_f32_16x16x32_bf16(ah[mi], bfr[bi][ni], acc[bi][mi][ni], 0, 0, 0);
    __builtin_amdgcn_s_setprio(0);
  }

  #pragma unroll
  for (int mi = 0; mi < 4; ++mi) {
    const int o0 = m0 + wm + mi * 16 + ((l >> 4) << 2);
    #pragma unroll
    for (int bi = 0; bi < 2; ++bi) {
      const int b = b0 + bi;
      #pragma unroll
      for (int ni = 0; ni < 2; ++ni) {
        const int n = n0 + wn + ni * 16 + (l & 15);
        if (n >= NPIX) continue;
        #pragma unroll
        for (int jr = 0; jr < 4; ++jr)
          out[((size_t)b * MID + o0 + jr) * NPIX + n] = acc[bi][mi][ni][jr] + bp[o0 + jr];
      }
    }
  }
}

extern "C" void kernel_launch(void* const* d_in, const int* in_sizes, int n_in,
                              void* d_out, int out_size, void* d_ws, size_t ws_size,
                              hipStream_t stream) {
  const float* x          = (const float*)d_in[0];
  const float* Wq         = (const float*)d_in[1];
  const float* bq         = (const float*)d_in[2];
  const float* Wkv        = (const float*)d_in[3];
  const float* bkv        = (const float*)d_in[4];
  const float* bias_table = (const float*)d_in[5];
  const float* Wproj      = (const float*)d_in[6];
  const float* bproj      = (const float*)d_in[7];
  const float* gamma      = (const float*)d_in[8];

  char* ws = (char*)d_ws;
  u16*   xT    = (u16*)(ws + 0);          //  9,633,792 B
  u16*   wqkv  = (u16*)(ws + 9633792);    //    884,736 B
  u16*   wp    = (u16*)(ws + 10518528);   //    294,912 B
  float* bqkv  = (float*)(ws + 10813440); //      4,608 B
  float* bp    = (float*)(ws + 10818048); //      1,536 B
  float* biasT = (float*)(ws + 10819584); //    145,200 B (pad to 145,408)
  u16*   q_s   = (u16*)(ws + 10964992);   //  9,633,792 B
  u16*   k_s   = (u16*)(ws + 20598784);   //  9,633,792 B
  u16*   vt    = (u16*)(ws + 30232576);   //  9,633,792 B
  u16*   oTb   = (u16*)(ws + 39866368);   //  9,633,792 B  (total ~49.5 MB)
  float* out   = (float*)d_out;

  prep_all<<<dim3(2752), dim3(256), 0, stream>>>(x, Wq, bq, Wkv, bkv, Wproj, bproj, gamma,
                                                 bias_table, wqkv, wp, bqkv, bp, biasT, xT);
  qkv_gemm<<<dim3(936), dim3(256), 0, stream>>>(wqkv, bqkv, xT, q_s, k_s, vt);
  attn<<<dim3(1344), dim3(448), 0, stream>>>(q_s, k_s, vt, biasT, oTb);
  proj_gemm<<<dim3(312), dim3(256), 0, stream>>>(wp, bp, oTb, out);
}